// Round 1
// baseline (710.902 us; speedup 1.0000x reference)
//
#include <hip/hip_runtime.h>
#include <hip/hip_bf16.h>
#include <stdint.h>

#define B_ 32
#define T_ 2048
#define H_ 1024
#define M_ (B_*T_)

typedef __bf16 bf16x8 __attribute__((ext_vector_type(8)));
typedef float  f32x4  __attribute__((ext_vector_type(4)));
typedef float  f32x16 __attribute__((ext_vector_type(16)));

__device__ __forceinline__ float tanh_fast(float x) {
    float e = __expf(2.0f * x);
    return 1.0f - 2.0f / (e + 1.0f);
}

__device__ __forceinline__ bf16x8 cvt2(f32x4 f0, f32x4 f1) {
    bf16x8 h;
    h[0] = (__bf16)f0[0]; h[1] = (__bf16)f0[1]; h[2] = (__bf16)f0[2]; h[3] = (__bf16)f0[3];
    h[4] = (__bf16)f1[0]; h[5] = (__bf16)f1[1]; h[6] = (__bf16)f1[2]; h[7] = (__bf16)f1[3];
    return h;
}

// ---------------- K0: fused prep (W_enc -> bf16 fragment tiles ; dec_p matvec) ----------------
__global__ __launch_bounds__(256) void k_prep(const float* __restrict__ We,
                                              __bf16* __restrict__ Wt,
                                              const float* __restrict__ dec,
                                              const float* __restrict__ Wd,
                                              float* __restrict__ decp) {
    int bx = blockIdx.x;
    int tid = threadIdx.x;
    if (bx < 512) {
        int tg = bx * 256 + tid;             // 131072 cells
        int lane = tg & 63;
        int c = (tg >> 6) & 31;
        int s = tg >> 11;                    // 0..63
        int o = c * 32 + (lane & 31);
        int k = s * 16 + (lane >> 5) * 8;
        const f32x4* src = (const f32x4*)&We[(size_t)o * H_ + k];
        *(bf16x8*)&Wt[(size_t)tg * 8] = cvt2(src[0], src[1]);
    } else {
        int bxd = bx - 512;
        int b = bxd & 31, oc = bxd >> 5;
        int o = oc * 64 + (tid >> 2);
        int kq = tid & 3;
        const f32x4* wr = (const f32x4*)&Wd[(size_t)o * H_ + kq * 256];
        const f32x4* dr = (const f32x4*)&dec[(size_t)b * H_ + kq * 256];
        f32x4 s4 = {0.f, 0.f, 0.f, 0.f};
#pragma unroll 8
        for (int i = 0; i < 64; ++i) s4 += wr[i] * dr[i];
        float s = s4[0] + s4[1] + s4[2] + s4[3];
        s += __shfl_xor(s, 1);
        s += __shfl_xor(s, 2);
        if (kq == 0) decp[b * H_ + o] = s;
    }
}

// ---------------- K1: fused GEMM(32x32x16) + tanh + dot(v) -> score partials ----------------
// 4096 blocks = 1024 row-groups (64 rows) x 4 col-groups (256 cols), 4 waves.
// SINGLE-buffered 32 KB A tile -> 4 blocks/CU (16 waves/CU) for TLP latency hiding.
// Staging: load+cvt to bf16 regs after the MFMA loop, barrier, LDS write, barrier.
// B: 2-deep register ring from L2-resident Wt. A ds_read: 2-deep ring.
__global__ __launch_bounds__(256, 4) void k_scores(const float* __restrict__ enc,
                                                   const float* __restrict__ decp,
                                                   const __bf16* __restrict__ Wt,
                                                   const float* __restrict__ v,
                                                   float* __restrict__ scores_p) {
    __shared__ __bf16 A_lds[64 * 32 * 8];   // 32 KB single buffer
    __shared__ float red[4][64];

    const int tid = threadIdx.x;
    const int w = tid >> 6, lane = tid & 63;
    const int l5 = lane & 31, q2 = lane >> 5;

    // XCD-swizzled block decode: 4 col-groups of a row-group land on one XCD (L2 A-reuse)
    const int bx = blockIdx.x;
    const int xs = bx & 7;
    const int q = bx >> 3;
    const int nt = q & 3;                   // col-group (256 cols)
    const int rg = (q >> 2) * 8 + xs;       // row-group 0..1023
    const int m0 = rg * 64;
    const int b = m0 >> 11;
    const int cg0 = nt * 8 + w * 2;         // global 32-col tile index

    float dp[2], vvv[2];
#pragma unroll
    for (int ct = 0; ct < 2; ++ct) {
        int col = (cg0 + ct) * 32 + l5;
        dp[ct]  = decp[b * H_ + col];
        vvv[ct] = v[col];
    }

    f32x16 acc[2][2];
#pragma unroll
    for (int rt = 0; rt < 2; ++rt)
#pragma unroll
        for (int ct = 0; ct < 2; ++ct)
#pragma unroll
            for (int g = 0; g < 16; ++g)
                acc[rt][ct][g] = dp[ct];

    // staging mapping: thread covers 8 rows x one k-octet
    const int ko_s = tid & 31;
    const int rbase = (tid >> 5) * 8;
    const float* sbase = &enc[(size_t)(m0 + rbase) * H_ + ko_s * 8];

    // ---- prologue: stage chunk 0 ----
    {
#pragma unroll
        for (int i = 0; i < 8; ++i) {
            const f32x4* s4 = (const f32x4*)(sbase + (size_t)i * H_);
            int row = rbase + i;
            int cell = row * 32 + ((ko_s & 24) | ((ko_s ^ row) & 7));
            *(bf16x8*)&A_lds[cell * 8] = cvt2(s4[0], s4[1]);
        }
    }

    // ---- B ring prologue: slices 0..1 (2-deep) ----
    bf16x8 bb[2][2];
#pragma unroll
    for (int p = 0; p < 2; ++p)
#pragma unroll
        for (int ct = 0; ct < 2; ++ct)
            bb[p][ct] = *(const bf16x8*)&Wt[(((size_t)p * 32 + cg0 + ct) * 64 + lane) * 8];

    __syncthreads();

#pragma unroll 1
    for (int kc = 0; kc < 4; ++kc) {
        // A ring prologue: sl = 0, 1
        bf16x8 af[2][2];
#pragma unroll
        for (int p = 0; p < 2; ++p)
#pragma unroll
            for (int rt = 0; rt < 2; ++rt) {
                int row = rt * 32 + l5;
                int ko = p * 2 + q2;
                int cell = row * 32 + ((ko & 24) | ((ko ^ row) & 7));
                af[p][rt] = *(const bf16x8*)&A_lds[cell * 8];
            }

#pragma unroll
        for (int sl = 0; sl < 16; ++sl) {
            const int s = kc * 16 + sl;
            bf16x8 a0 = af[sl & 1][0], a1 = af[sl & 1][1];
            bf16x8 w0 = bb[s & 1][0],  w1 = bb[s & 1][1];

            // prefetch B slice s+2 into the slot just freed
            {
                int sn = (s + 2) & 63;
#pragma unroll
                for (int ct = 0; ct < 2; ++ct)
                    bb[s & 1][ct] = *(const bf16x8*)&Wt[(((size_t)sn * 32 + cg0 + ct) * 64 + lane) * 8];
            }
            // prefetch A slice sl+2 (compile-time skip on last two: would wrap)
            if (sl < 14) {
                int sl2 = sl + 2;
#pragma unroll
                for (int rt = 0; rt < 2; ++rt) {
                    int row = rt * 32 + l5;
                    int ko = sl2 * 2 + q2;
                    int cell = row * 32 + ((ko & 24) | ((ko ^ row) & 7));
                    af[sl & 1][rt] = *(const bf16x8*)&A_lds[cell * 8];
                }
            }

            acc[0][0] = __builtin_amdgcn_mfma_f32_32x32x16_bf16(a0, w0, acc[0][0], 0, 0, 0);
            acc[0][1] = __builtin_amdgcn_mfma_f32_32x32x16_bf16(a0, w1, acc[0][1], 0, 0, 0);
            acc[1][0] = __builtin_amdgcn_mfma_f32_32x32x16_bf16(a1, w0, acc[1][0], 0, 0, 0);
            acc[1][1] = __builtin_amdgcn_mfma_f32_32x32x16_bf16(a1, w1, acc[1][1], 0, 0, 0);
        }

        // stage chunk kc+1: load+cvt (exposed latency hidden by 3 other resident blocks)
        if (kc < 3) {
            bf16x8 st[8];
            const float* sp0 = sbase + (size_t)(kc + 1) * 256;
#pragma unroll
            for (int i = 0; i < 8; ++i) {
                const f32x4* s4 = (const f32x4*)(sp0 + (size_t)i * H_);
                st[i] = cvt2(s4[0], s4[1]);
            }
            __syncthreads();            // all reads of A_lds done (uniform)
#pragma unroll
            for (int i = 0; i < 8; ++i) {
                int row = rbase + i;
                int cell = row * 32 + ((ko_s & 24) | ((ko_s ^ row) & 7));
                *(bf16x8*)&A_lds[cell * 8] = st[i];
            }
            __syncthreads();            // writes visible (uniform)
        }
    }

    // ---- epilogue ----
    float sp[2][16];
#pragma unroll
    for (int rt = 0; rt < 2; ++rt)
#pragma unroll
        for (int g = 0; g < 16; ++g)
            sp[rt][g] = tanh_fast(acc[rt][0][g]) * vvv[0] + tanh_fast(acc[rt][1][g]) * vvv[1];

#pragma unroll
    for (int rt = 0; rt < 2; ++rt)
#pragma unroll
        for (int g = 0; g < 16; ++g) {
            float s = sp[rt][g];
            s += __shfl_xor(s, 1);
            s += __shfl_xor(s, 2);
            s += __shfl_xor(s, 4);
            s += __shfl_xor(s, 8);
            s += __shfl_xor(s, 16);
            sp[rt][g] = s;
        }

    __syncthreads();
    if (l5 == 0) {
#pragma unroll
        for (int rt = 0; rt < 2; ++rt)
#pragma unroll
            for (int g = 0; g < 16; ++g) {
                int row = rt * 32 + (g & 3) + 8 * (g >> 2) + 4 * q2;
                red[w][row] = sp[rt][g];
            }
    }
    __syncthreads();
    if (tid < 64) {
        float s = red[0][tid] + red[1][tid] + red[2][tid] + red[3][tid];
        scores_p[nt * M_ + m0 + tid] = s;   // per-col-group partial, no atomics
    }
}

// ---------------- K2: sum partials + masked softmax ----------------
__global__ __launch_bounds__(256) void k_softmax(const float* __restrict__ scores_p,
                                                 const int* __restrict__ mask,
                                                 float* __restrict__ attn) {
    int b = blockIdx.x;
    int tid = threadIdx.x;
    int w = tid >> 6, lane = tid & 63;
    __shared__ float sm[2][4];
    float val[8];
    float mx = -3e38f;
#pragma unroll
    for (int ii = 0; ii < 8; ++ii) {
        int idx = b * T_ + tid + ii * 256;
        float s = scores_p[idx] + scores_p[M_ + idx] + scores_p[2 * M_ + idx] + scores_p[3 * M_ + idx];
        s = (mask[idx] == 0) ? -1e9f : s;
        val[ii] = s;
        mx = fmaxf(mx, s);
    }
#pragma unroll
    for (int m = 1; m <= 32; m <<= 1) mx = fmaxf(mx, __shfl_xor(mx, m));
    if (lane == 0) sm[0][w] = mx;
    __syncthreads();
    mx = fmaxf(fmaxf(sm[0][0], sm[0][1]), fmaxf(sm[0][2], sm[0][3]));
    float lsum = 0.f;
#pragma unroll
    for (int ii = 0; ii < 8; ++ii) {
        val[ii] = __expf(val[ii] - mx);
        lsum += val[ii];
    }
#pragma unroll
    for (int m = 1; m <= 32; m <<= 1) lsum += __shfl_xor(lsum, m);
    if (lane == 0) sm[1][w] = lsum;
    __syncthreads();
    float inv = 1.0f / (sm[1][0] + sm[1][1] + sm[1][2] + sm[1][3]);
#pragma unroll
    for (int ii = 0; ii < 8; ++ii)
        attn[b * T_ + tid + ii * 256] = val[ii] * inv;
}

// ---------------- K3: partial context over T-segments, fully-contiguous enc streaming ----------
// 1024 blocks = 32 b x 32 segs of 64 rows. Block covers ALL 1024 cols: each row read is a
// contiguous 4 KB stream (4 waves x 1 KB) -> pure HBM stream, 4 blocks/CU.
__global__ __launch_bounds__(256) void k_context(const float* __restrict__ enc,
                                                 const float* __restrict__ attn,
                                                 float* __restrict__ ctxp) {
    int bx = blockIdx.x;
    int b = bx >> 5, seg = bx & 31;
    int t0 = seg * 64;
    const float* ep = &enc[((size_t)b * T_ + t0) * H_ + threadIdx.x * 4];
    const float* ap = &attn[b * T_ + t0];
    f32x4 acc = {0.f, 0.f, 0.f, 0.f};
#pragma unroll 8
    for (int t = 0; t < 64; ++t) {
        float a = ap[t];                       // block-uniform -> scalar load
        acc += a * *(const f32x4*)(ep + (size_t)t * H_);
    }
    *(f32x4*)&ctxp[((size_t)seg * B_ + b) * H_ + threadIdx.x * 4] = acc;
}

// ---------------- K4: deterministic reduce of the 32 segment partials ----------------
__global__ __launch_bounds__(256) void k_ctxred(const float* __restrict__ ctxp,
                                                float* __restrict__ ctx) {
    int i = blockIdx.x * 256 + threadIdx.x;    // 0..32767 over b*H+h
    float s = 0.f;
#pragma unroll
    for (int sg = 0; sg < 32; ++sg)
        s += ctxp[(size_t)sg * (B_ * H_) + i];
    ctx[i] = s;
}

extern "C" void kernel_launch(void* const* d_in, const int* in_sizes, int n_in,
                              void* d_out, int out_size, void* d_ws, size_t ws_size,
                              hipStream_t stream) {
    (void)in_sizes; (void)n_in; (void)out_size; (void)ws_size;
    const float* dec  = (const float*)d_in[0];
    const float* enc  = (const float*)d_in[1];
    const int*   mask = (const int*)d_in[2];
    const float* We   = (const float*)d_in[3];
    const float* Wd   = (const float*)d_in[4];
    const float* v    = (const float*)d_in[5];

    float* out = (float*)d_out;                 // [0,32768) context ; [32768,98304) attn
    char* ws = (char*)d_ws;
    float*  decp     = (float*)ws;                          // 128 KB
    float*  scores_p = (float*)(ws + 131072);               // 4 x 256 KB = 1 MB (dead after softmax)
    __bf16* Wt       = (__bf16*)(ws + 131072 + 1048576);    // 2 MB (dead after k_scores)
    // ctxp (4 MB) aliases scores_p+Wt (both dead by k_context; same-stream ordering)
    float*  ctxp     = (float*)(ws + 131072);

    k_prep   <<<1024, 256, 0, stream>>>(We, Wt, dec, Wd, decp);
    k_scores <<<4096, 256, 0, stream>>>(enc, decp, Wt, v, scores_p);
    k_softmax<<<32, 256, 0, stream>>>(scores_p, mask, out + B_ * H_);
    k_context<<<1024, 256, 0, stream>>>(enc, out + B_ * H_, ctxp);
    k_ctxred <<<128, 256, 0, stream>>>(ctxp, out);
}

// Round 2
// 626.703 us; speedup vs baseline: 1.1344x; 1.1344x over previous
//
#include <hip/hip_runtime.h>
#include <hip/hip_bf16.h>
#include <stdint.h>

#define B_ 32
#define T_ 2048
#define H_ 1024
#define M_ (B_*T_)

typedef __bf16 bf16x8 __attribute__((ext_vector_type(8)));
typedef float  f32x4  __attribute__((ext_vector_type(4)));
typedef float  f32x16 __attribute__((ext_vector_type(16)));

__device__ __forceinline__ float tanh_fast(float x) {
    float e = __expf(2.0f * x);
    return 1.0f - 2.0f / (e + 1.0f);
}

__device__ __forceinline__ bf16x8 cvt2(f32x4 f0, f32x4 f1) {
    bf16x8 h;
    h[0] = (__bf16)f0[0]; h[1] = (__bf16)f0[1]; h[2] = (__bf16)f0[2]; h[3] = (__bf16)f0[3];
    h[4] = (__bf16)f1[0]; h[5] = (__bf16)f1[1]; h[6] = (__bf16)f1[2]; h[7] = (__bf16)f1[3];
    return h;
}

// async 16B global->LDS (HW writes wave-uniform-base + lane*16; our tile order IS lane order)
__device__ __forceinline__ void gl_lds16(const __bf16* g, __bf16* l) {
    __builtin_amdgcn_global_load_lds(
        (const __attribute__((address_space(1))) void*)g,
        (__attribute__((address_space(3))) void*)l, 16, 0, 0);
}

// ---------------- K0: fused prep (W_enc -> bf16 fragment tiles ; dec_p matvec) ----------------
__global__ __launch_bounds__(256) void k_prep(const float* __restrict__ We,
                                              __bf16* __restrict__ Wt,
                                              const float* __restrict__ dec,
                                              const float* __restrict__ Wd,
                                              float* __restrict__ decp) {
    int bx = blockIdx.x;
    int tid = threadIdx.x;
    if (bx < 512) {
        int tg = bx * 256 + tid;             // 131072 cells
        int lane = tg & 63;
        int c = (tg >> 6) & 31;
        int s = tg >> 11;                    // 0..63
        int o = c * 32 + (lane & 31);
        int k = s * 16 + (lane >> 5) * 8;
        const f32x4* src = (const f32x4*)&We[(size_t)o * H_ + k];
        *(bf16x8*)&Wt[(size_t)tg * 8] = cvt2(src[0], src[1]);
    } else {
        int bxd = bx - 512;
        int b = bxd & 31, oc = bxd >> 5;
        int o = oc * 64 + (tid >> 2);
        int kq = tid & 3;
        const f32x4* wr = (const f32x4*)&Wd[(size_t)o * H_ + kq * 256];
        const f32x4* dr = (const f32x4*)&dec[(size_t)b * H_ + kq * 256];
        f32x4 s4 = {0.f, 0.f, 0.f, 0.f};
#pragma unroll 8
        for (int i = 0; i < 64; ++i) s4 += wr[i] * dr[i];
        float s = s4[0] + s4[1] + s4[2] + s4[3];
        s += __shfl_xor(s, 1);
        s += __shfl_xor(s, 2);
        if (kq == 0) decp[b * H_ + o] = s;
    }
}

// ---------------- K0b: enc f32 -> bf16 in MFMA A-fragment tile order ----------------
// enc_t[rg][s][rt][lane] bf16x8 : cell holds enc[rg*64 + rt*32 + (lane&31)][s*16 + (lane>>5)*8 ..+8]
// 2048 blocks = 1024 rg x 2 rt. Per wave-iter each row reads a full 128B line; writes are
// 512B-contiguous per 32 lanes.
__global__ __launch_bounds__(256) void k_prep_enc(const float* __restrict__ enc,
                                                  __bf16* __restrict__ enc_t) {
    int bx = blockIdx.x;
    int rg = bx >> 1, rt = bx & 1;
    int tid = threadIdx.x;
    int w = tid >> 6, lane = tid & 63;
    int l5 = lane & 31, sh = lane >> 5;
    int row = rg * 64 + rt * 32 + l5;
    const float* src = &enc[(size_t)row * H_];
#pragma unroll 2
    for (int i = 0; i < 8; ++i) {
        int s = (w + 4 * i) * 2 + sh;                 // 0..63, each once across block
        const f32x4* s4 = (const f32x4*)(src + s * 16);
        bf16x8 h0 = cvt2(s4[0], s4[1]);               // k-octet q2=0
        bf16x8 h1 = cvt2(s4[2], s4[3]);               // k-octet q2=1
        size_t base = ((size_t)(rg * 64 + s) * 2 + rt) * 64;
        *(bf16x8*)&enc_t[(base + l5) * 8]      = h0;
        *(bf16x8*)&enc_t[(base + 32 + l5) * 8] = h1;
    }
}

// ---------------- K1: fused GEMM(32x32x16) + tanh + dot(v) -> score partials ----------------
// 4096 blocks = 1024 row-groups (64 rows) x 4 col-groups (256 cols), 4 waves, wave = 64x64.
// A staged from pre-tiled bf16 enc_t via global_load_lds(16B): linear LDS, no cvt VALU,
// no staging registers -> fits 128 VGPR cap -> 4 blocks/CU (LDS 33 KB).
// Double-buffered 16 KB chunks (128 k each), async prefetch in flight across the MFMA loop.
__global__ __launch_bounds__(256, 4) void k_scores(const __bf16* __restrict__ enc_t,
                                                   const float* __restrict__ decp,
                                                   const __bf16* __restrict__ Wt,
                                                   const float* __restrict__ v,
                                                   float* __restrict__ scores_p) {
    __shared__ __bf16 A_lds[2][8192];   // 2 x 16 KB: [sl 0..7][rt 0..1][lane 0..63] bf16x8
    __shared__ float red[4][64];

    const int tid = threadIdx.x;
    const int w = tid >> 6, lane = tid & 63;
    const int l5 = lane & 31, q2 = lane >> 5;

    // XCD-swizzled decode: the 4 col-groups of one row-group share an XCD (L2 A-reuse)
    const int bx = blockIdx.x;
    const int xs = bx & 7;
    const int q = bx >> 3;
    const int nt = q & 3;                   // col-group (256 cols)
    const int rg = (q >> 2) * 8 + xs;       // row-group 0..1023
    const int m0 = rg * 64;
    const int b = m0 >> 11;
    const int cg0 = nt * 8 + w * 2;         // global 32-col tile index

    float dp[2], vvv[2];
#pragma unroll
    for (int ct = 0; ct < 2; ++ct) {
        int col = (cg0 + ct) * 32 + l5;
        dp[ct]  = decp[b * H_ + col];
        vvv[ct] = v[col];
    }

    f32x16 acc[2][2];
#pragma unroll
    for (int rt = 0; rt < 2; ++rt)
#pragma unroll
        for (int ct = 0; ct < 2; ++ct)
#pragma unroll
            for (int g = 0; g < 16; ++g)
                acc[rt][ct][g] = dp[ct];

    // staging source: thread's cell c = i*256 + tid of chunk ck
    const __bf16* gsrc = enc_t + (size_t)rg * 65536 + (size_t)tid * 8;

    // ---- prologue: stage chunk 0 into buf 0 ----
#pragma unroll
    for (int i = 0; i < 4; ++i)
        gl_lds16(gsrc + i * 2048, &A_lds[0][(i * 256 + tid) * 8]);

    // ---- B ring prologue: slices 0..1 ----
    bf16x8 bb[2][2];
#pragma unroll
    for (int p = 0; p < 2; ++p)
#pragma unroll
        for (int ct = 0; ct < 2; ++ct)
            bb[p][ct] = *(const bf16x8*)&Wt[(((size_t)p * 32 + cg0 + ct) * 64 + lane) * 8];

    __syncthreads();   // drains vmcnt(0): chunk 0 staged, all waves

    int buf = 0;
#pragma unroll 1
    for (int ck = 0; ck < 8; ++ck) {
        // issue async stage of chunk ck+1 into the other buffer; in flight across MFMAs
        if (ck < 7) {
            const __bf16* gs = gsrc + (size_t)(ck + 1) * 8192;
            __bf16* dst = A_lds[buf ^ 1];
#pragma unroll
            for (int i = 0; i < 4; ++i)
                gl_lds16(gs + i * 2048, &dst[(i * 256 + tid) * 8]);
        }

        const __bf16* bufp = A_lds[buf];

        // A ring prologue: sl = 0, 1 (linear conflict-free ds_read_b128)
        bf16x8 af[2][2];
#pragma unroll
        for (int p = 0; p < 2; ++p)
#pragma unroll
            for (int rt = 0; rt < 2; ++rt)
                af[p][rt] = *(const bf16x8*)&bufp[((p * 2 + rt) * 64 + lane) * 8];

#pragma unroll
        for (int sl = 0; sl < 8; ++sl) {
            const int s = ck * 8 + sl;
            bf16x8 a0 = af[sl & 1][0], a1 = af[sl & 1][1];
            bf16x8 w0 = bb[sl & 1][0], w1 = bb[sl & 1][1];

            // prefetch B slice s+2 (L2-resident Wt) into the slot just freed
            {
                int sn = (s + 2) & 63;
#pragma unroll
                for (int ct = 0; ct < 2; ++ct)
                    bb[sl & 1][ct] = *(const bf16x8*)&Wt[(((size_t)sn * 32 + cg0 + ct) * 64 + lane) * 8];
            }
            // prefetch A slice sl+2 (skip at chunk tail)
            if (sl < 6) {
                int sl2 = sl + 2;
#pragma unroll
                for (int rt = 0; rt < 2; ++rt)
                    af[sl & 1][rt] = *(const bf16x8*)&bufp[((sl2 * 2 + rt) * 64 + lane) * 8];
            }

            acc[0][0] = __builtin_amdgcn_mfma_f32_32x32x16_bf16(a0, w0, acc[0][0], 0, 0, 0);
            acc[0][1] = __builtin_amdgcn_mfma_f32_32x32x16_bf16(a0, w1, acc[0][1], 0, 0, 0);
            acc[1][0] = __builtin_amdgcn_mfma_f32_32x32x16_bf16(a1, w0, acc[1][0], 0, 0, 0);
            acc[1][1] = __builtin_amdgcn_mfma_f32_32x32x16_bf16(a1, w1, acc[1][1], 0, 0, 0);
        }

        __syncthreads();   // drains vmcnt(0): chunk ck+1 staged; all reads of buf done
        buf ^= 1;
    }

    // ---- epilogue ----
    float sp[2][16];
#pragma unroll
    for (int rt = 0; rt < 2; ++rt)
#pragma unroll
        for (int g = 0; g < 16; ++g)
            sp[rt][g] = tanh_fast(acc[rt][0][g]) * vvv[0] + tanh_fast(acc[rt][1][g]) * vvv[1];

#pragma unroll
    for (int rt = 0; rt < 2; ++rt)
#pragma unroll
        for (int g = 0; g < 16; ++g) {
            float s = sp[rt][g];
            s += __shfl_xor(s, 1);
            s += __shfl_xor(s, 2);
            s += __shfl_xor(s, 4);
            s += __shfl_xor(s, 8);
            s += __shfl_xor(s, 16);
            sp[rt][g] = s;
        }

    if (l5 == 0) {
#pragma unroll
        for (int rt = 0; rt < 2; ++rt)
#pragma unroll
            for (int g = 0; g < 16; ++g) {
                int row = rt * 32 + (g & 3) + 8 * (g >> 2) + 4 * q2;
                red[w][row] = sp[rt][g];
            }
    }
    __syncthreads();
    if (tid < 64) {
        float s = red[0][tid] + red[1][tid] + red[2][tid] + red[3][tid];
        scores_p[nt * M_ + m0 + tid] = s;   // per-col-group partial, no atomics
    }
}

// ---------------- K2: sum partials + masked softmax ----------------
__global__ __launch_bounds__(256) void k_softmax(const float* __restrict__ scores_p,
                                                 const int* __restrict__ mask,
                                                 float* __restrict__ attn) {
    int b = blockIdx.x;
    int tid = threadIdx.x;
    int w = tid >> 6, lane = tid & 63;
    __shared__ float sm[2][4];
    float val[8];
    float mx = -3e38f;
#pragma unroll
    for (int ii = 0; ii < 8; ++ii) {
        int idx = b * T_ + tid + ii * 256;
        float s = scores_p[idx] + scores_p[M_ + idx] + scores_p[2 * M_ + idx] + scores_p[3 * M_ + idx];
        s = (mask[idx] == 0) ? -1e9f : s;
        val[ii] = s;
        mx = fmaxf(mx, s);
    }
#pragma unroll
    for (int m = 1; m <= 32; m <<= 1) mx = fmaxf(mx, __shfl_xor(mx, m));
    if (lane == 0) sm[0][w] = mx;
    __syncthreads();
    mx = fmaxf(fmaxf(sm[0][0], sm[0][1]), fmaxf(sm[0][2], sm[0][3]));
    float lsum = 0.f;
#pragma unroll
    for (int ii = 0; ii < 8; ++ii) {
        val[ii] = __expf(val[ii] - mx);
        lsum += val[ii];
    }
#pragma unroll
    for (int m = 1; m <= 32; m <<= 1) lsum += __shfl_xor(lsum, m);
    if (lane == 0) sm[1][w] = lsum;
    __syncthreads();
    float inv = 1.0f / (sm[1][0] + sm[1][1] + sm[1][2] + sm[1][3]);
#pragma unroll
    for (int ii = 0; ii < 8; ++ii)
        attn[b * T_ + tid + ii * 256] = val[ii] * inv;
}

// ---------------- K3: partial context over T-segments, fully-contiguous enc streaming ----------
__global__ __launch_bounds__(256) void k_context(const float* __restrict__ enc,
                                                 const float* __restrict__ attn,
                                                 float* __restrict__ ctxp) {
    int bx = blockIdx.x;
    int b = bx >> 5, seg = bx & 31;
    int t0 = seg * 64;
    const float* ep = &enc[((size_t)b * T_ + t0) * H_ + threadIdx.x * 4];
    const float* ap = &attn[b * T_ + t0];
    f32x4 acc = {0.f, 0.f, 0.f, 0.f};
#pragma unroll 8
    for (int t = 0; t < 64; ++t) {
        float a = ap[t];                       // block-uniform -> scalar load
        acc += a * *(const f32x4*)(ep + (size_t)t * H_);
    }
    *(f32x4*)&ctxp[((size_t)seg * B_ + b) * H_ + threadIdx.x * 4] = acc;
}

// ---------------- K4: deterministic reduce of the 32 segment partials ----------------
__global__ __launch_bounds__(256) void k_ctxred(const float* __restrict__ ctxp,
                                                float* __restrict__ ctx) {
    int i = blockIdx.x * 256 + threadIdx.x;    // 0..32767 over b*H+h
    float s = 0.f;
#pragma unroll
    for (int sg = 0; sg < 32; ++sg)
        s += ctxp[(size_t)sg * (B_ * H_) + i];
    ctx[i] = s;
}

extern "C" void kernel_launch(void* const* d_in, const int* in_sizes, int n_in,
                              void* d_out, int out_size, void* d_ws, size_t ws_size,
                              hipStream_t stream) {
    (void)in_sizes; (void)n_in; (void)out_size; (void)ws_size;
    const float* dec  = (const float*)d_in[0];
    const float* enc  = (const float*)d_in[1];
    const int*   mask = (const int*)d_in[2];
    const float* We   = (const float*)d_in[3];
    const float* Wd   = (const float*)d_in[4];
    const float* v    = (const float*)d_in[5];

    float* out = (float*)d_out;                 // [0,32768) context ; [32768,98304) attn
    char* ws = (char*)d_ws;
    float*  decp     = (float*)ws;                          // 128 KB
    float*  scores_p = (float*)(ws + 131072);               // 1 MB (dead after softmax)
    __bf16* Wt       = (__bf16*)(ws + 131072 + 1048576);    // 2 MB (dead after k_scores)
    __bf16* enc_t    = (__bf16*)(ws + 131072 + 1048576 + 2097152);  // 128 MB (dead after k_scores)
    float*  ctxp     = (float*)(ws + 131072 + 1048576 + 2097152);   // 4 MB, aliases enc_t

    k_prep    <<<1024, 256, 0, stream>>>(We, Wt, dec, Wd, decp);
    k_prep_enc<<<2048, 256, 0, stream>>>(enc, enc_t);
    k_scores  <<<4096, 256, 0, stream>>>(enc_t, decp, Wt, v, scores_p);
    k_softmax <<<32, 256, 0, stream>>>(scores_p, mask, out + B_ * H_);
    k_context <<<1024, 256, 0, stream>>>(enc, out + B_ * H_, ctxp);
    k_ctxred  <<<128, 256, 0, stream>>>(ctxp, out);
}

// Round 3
// 569.807 us; speedup vs baseline: 1.2476x; 1.0999x over previous
//
#include <hip/hip_runtime.h>
#include <hip/hip_bf16.h>
#include <stdint.h>

#define B_ 32
#define T_ 2048
#define H_ 1024
#define M_ (B_*T_)

typedef __bf16 bf16x8 __attribute__((ext_vector_type(8)));
typedef float  f32x4  __attribute__((ext_vector_type(4)));
typedef float  f32x16 __attribute__((ext_vector_type(16)));

__device__ __forceinline__ float tanh_fast(float x) {
    float e = __expf(2.0f * x);
    return 1.0f - 2.0f / (e + 1.0f);
}

__device__ __forceinline__ bf16x8 cvt2(f32x4 f0, f32x4 f1) {
    bf16x8 h;
    h[0] = (__bf16)f0[0]; h[1] = (__bf16)f0[1]; h[2] = (__bf16)f0[2]; h[3] = (__bf16)f0[3];
    h[4] = (__bf16)f1[0]; h[5] = (__bf16)f1[1]; h[6] = (__bf16)f1[2]; h[7] = (__bf16)f1[3];
    return h;
}

// async 16B global->LDS (HW dest = wave-uniform base + lane*16)
__device__ __forceinline__ void gl_lds16f(const float* g, float* l) {
    __builtin_amdgcn_global_load_lds(
        (const __attribute__((address_space(1))) void*)g,
        (__attribute__((address_space(3))) void*)l, 16, 0, 0);
}

// ---------------- K0: fused prep (W_enc -> bf16 fragment tiles ; dec_p matvec) ----------------
__global__ __launch_bounds__(256) void k_prep(const float* __restrict__ We,
                                              __bf16* __restrict__ Wt,
                                              const float* __restrict__ dec,
                                              const float* __restrict__ Wd,
                                              float* __restrict__ decp) {
    int bx = blockIdx.x;
    int tid = threadIdx.x;
    if (bx < 512) {
        int tg = bx * 256 + tid;             // 131072 cells
        int lane = tg & 63;
        int c = (tg >> 6) & 31;
        int s = tg >> 11;                    // 0..63
        int o = c * 32 + (lane & 31);
        int k = s * 16 + (lane >> 5) * 8;
        const f32x4* src = (const f32x4*)&We[(size_t)o * H_ + k];
        *(bf16x8*)&Wt[(size_t)tg * 8] = cvt2(src[0], src[1]);
    } else {
        int bxd = bx - 512;
        int b = bxd & 31, oc = bxd >> 5;
        int o = oc * 64 + (tid >> 2);
        int kq = tid & 3;
        const f32x4* wr = (const f32x4*)&Wd[(size_t)o * H_ + kq * 256];
        const f32x4* dr = (const f32x4*)&dec[(size_t)b * H_ + kq * 256];
        f32x4 s4 = {0.f, 0.f, 0.f, 0.f};
#pragma unroll 8
        for (int i = 0; i < 64; ++i) s4 += wr[i] * dr[i];
        float s = s4[0] + s4[1] + s4[2] + s4[3];
        s += __shfl_xor(s, 1);
        s += __shfl_xor(s, 2);
        if (kq == 0) decp[b * H_ + o] = s;
    }
}

// ---------------- K1: fused GEMM(32x32x16) + tanh + dot(v) -> score partials ----------------
// 4096 blocks = 1024 row-groups (64 rows) x 4 col-groups (256 cols), 4 waves.
// A: f32 enc staged directly via global_load_lds into a 3-buffer XOR-swizzled LDS ring
// (3 x 16 KB, chunk = 64 rows x 64 k). Swizzle: kbyte ^= (row&7)<<4, applied on the
// pre-swizzled GLOBAL source (linear LDS dest) and on the ds_read address (rule #21).
// Ordered streams: per chunk [compute | raw s_barrier | BLOAD(ck+1) | STAGE(ck+3)].
// Bload(j+1) issued BEFORE stage(j+3) => compiler's in-order vmcnt wait on B(ck)
// retires exactly staging(ck+1), keeping staging(ck+2),(ck+3) in flight: 2-window
// lookahead with NO vmcnt(0) drain in the loop. cvt f32->bf16 in-reg after ds_read.
__global__ __launch_bounds__(256, 3) void k_scores(const float* __restrict__ enc,
                                                   const float* __restrict__ decp,
                                                   const __bf16* __restrict__ Wt,
                                                   const float* __restrict__ v,
                                                   float* __restrict__ scores_p) {
    __shared__ float A_lds[3 * 4096];   // 3 x 16 KB f32 chunks
    __shared__ float red[4][64];

    const int tid = threadIdx.x;
    const int w = tid >> 6, lane = tid & 63;
    const int l5 = lane & 31, q2 = lane >> 5;

    // XCD-swizzled decode: the 4 col-groups of one row-group share an XCD (L2 A-reuse)
    const int bx = blockIdx.x;
    const int xs = bx & 7;
    const int q = bx >> 3;
    const int nt = q & 3;                   // col-group (256 cols)
    const int rg = (q >> 2) * 8 + xs;       // row-group 0..1023
    const int m0 = rg * 64;
    const int b = m0 >> 11;
    const int cg0 = nt * 8 + w * 2;         // global 32-col tile index

    float dp[2], vvv[2];
#pragma unroll
    for (int ct = 0; ct < 2; ++ct) {
        int col = (cg0 + ct) * 32 + l5;
        dp[ct]  = decp[b * H_ + col];
        vvv[ct] = v[col];
    }

    f32x16 acc[2][2];
#pragma unroll
    for (int rt = 0; rt < 2; ++rt)
#pragma unroll
        for (int ct = 0; ct < 2; ++ct)
#pragma unroll
            for (int g = 0; g < 16; ++g)
                acc[rt][ct][g] = dp[ct];

    // staging geometry: wave w instr i covers rows [w*16+4i, +4); lane -> row 4i+(lane>>4),
    // within-row phys float off (lane&15)*4; logical k = phys ^ ((row&7)<<2) (float units)
    const int srow = w * 16 + (lane >> 4);              // i=0 row
    const int sof  = ((lane & 15) * 4) ^ ((srow & 7) << 2);
    const int ld0  = w * 4 * 256 + lane * 4;            // LDS float offset, i=0

#define STAGE(ck_, cb_) do { \
    _Pragma("unroll") \
    for (int i_ = 0; i_ < 4; ++i_) { \
        int row_ = srow + 4 * i_; \
        int of_  = sof ^ ((i_ & 1) << 4); \
        gl_lds16f(enc + (size_t)(m0 + row_) * H_ + (ck_) * 64 + of_, \
                  &A_lds[(cb_) * 4096 + ld0 + i_ * 256]); \
    } } while (0)

    bf16x8 bb[4][2];
#define BLOAD(ck_) do { \
    _Pragma("unroll") \
    for (int sl_ = 0; sl_ < 4; ++sl_) \
        _Pragma("unroll") \
        for (int ct_ = 0; ct_ < 2; ++ct_) \
            bb[sl_][ct_] = *(const bf16x8*)&Wt[(((size_t)((ck_) * 4 + sl_) * 32 + cg0 + ct_) * 64 + lane) * 8]; \
    } while (0)

    // ---- prologue: stage chunks 0,1,2 ; B for chunk 0 ----
    STAGE(0, 0);
    STAGE(1, 1);
    STAGE(2, 2);
    BLOAD(0);
    __builtin_amdgcn_sched_barrier(0);
    asm volatile("s_waitcnt vmcnt(8)" ::: "memory");   // stagings 0..2 landed (B may fly)
    __builtin_amdgcn_s_barrier();
    __builtin_amdgcn_sched_barrier(0);

    int cb = 0;
#pragma unroll 1
    for (int ck = 0; ck < 16; ++ck) {
        const float* bufp = &A_lds[cb * 4096];

        // ---- compute chunk ck: 4 slices x 4 MFMA; no vmem in this section ----
#pragma unroll
        for (int sl = 0; sl < 4; ++sl) {
            bf16x8 a[2];
#pragma unroll
            for (int rt = 0; rt < 2; ++rt) {
                int row = rt * 32 + l5;
                int kf  = sl * 16 + q2 * 8;
                int sw  = (row & 7) << 2;
                f32x4 lo = *(const f32x4*)&bufp[row * 64 + (kf ^ sw)];
                f32x4 hi = *(const f32x4*)&bufp[row * 64 + ((kf + 4) ^ sw)];
                a[rt] = cvt2(lo, hi);
            }
            acc[0][0] = __builtin_amdgcn_mfma_f32_32x32x16_bf16(a[0], bb[sl][0], acc[0][0], 0, 0, 0);
            acc[0][1] = __builtin_amdgcn_mfma_f32_32x32x16_bf16(a[0], bb[sl][1], acc[0][1], 0, 0, 0);
            acc[1][0] = __builtin_amdgcn_mfma_f32_32x32x16_bf16(a[1], bb[sl][0], acc[1][0], 0, 0, 0);
            acc[1][1] = __builtin_amdgcn_mfma_f32_32x32x16_bf16(a[1], bb[sl][1], acc[1][1], 0, 0, 0);
        }

        __builtin_amdgcn_sched_barrier(0);
        asm volatile("" ::: "memory");
        __builtin_amdgcn_s_barrier();                  // raw: NO vmcnt(0) drain
        asm volatile("" ::: "memory");
        __builtin_amdgcn_sched_barrier(0);

        if (ck < 15) BLOAD(ck + 1);                    // B first (older than next staging!)
        __builtin_amdgcn_sched_barrier(0);
        if (ck < 13) STAGE(ck + 3, cb);                // reuse the buffer just computed from
        __builtin_amdgcn_sched_barrier(0);

        cb = cb + 1; if (cb == 3) cb = 0;
    }
#undef STAGE
#undef BLOAD

    // ---- epilogue ----
    float sp[2][16];
#pragma unroll
    for (int rt = 0; rt < 2; ++rt)
#pragma unroll
        for (int g = 0; g < 16; ++g)
            sp[rt][g] = tanh_fast(acc[rt][0][g]) * vvv[0] + tanh_fast(acc[rt][1][g]) * vvv[1];

#pragma unroll
    for (int rt = 0; rt < 2; ++rt)
#pragma unroll
        for (int g = 0; g < 16; ++g) {
            float s = sp[rt][g];
            s += __shfl_xor(s, 1);
            s += __shfl_xor(s, 2);
            s += __shfl_xor(s, 4);
            s += __shfl_xor(s, 8);
            s += __shfl_xor(s, 16);
            sp[rt][g] = s;
        }

    __syncthreads();
    if (l5 == 0) {
#pragma unroll
        for (int rt = 0; rt < 2; ++rt)
#pragma unroll
            for (int g = 0; g < 16; ++g) {
                int row = rt * 32 + (g & 3) + 8 * (g >> 2) + 4 * q2;
                red[w][row] = sp[rt][g];
            }
    }
    __syncthreads();
    if (tid < 64) {
        float s = red[0][tid] + red[1][tid] + red[2][tid] + red[3][tid];
        scores_p[nt * M_ + m0 + tid] = s;   // per-col-group partial, no atomics
    }
}

// ---------------- K2: fused masked-softmax + context partial ----------------
// 512 blocks = 32 b x 16 segs of 128 rows. Each block redundantly computes the full
// softmax for its batch (40 KB reads, ~free), then streams its 128-row enc segment
// contiguously (4 KB/row). seg==0 block writes the attn output row.
__global__ __launch_bounds__(256) void k_ctx(const float* __restrict__ scores_p,
                                             const int* __restrict__ mask,
                                             const float* __restrict__ enc,
                                             float* __restrict__ attn,
                                             float* __restrict__ ctxp) {
    int bx = blockIdx.x;
    int b = bx >> 4, seg = bx & 15;
    int tid = threadIdx.x;
    int w = tid >> 6, lane = tid & 63;
    __shared__ float sm[2][4];
    __shared__ float wa[128];

    float val[8];
    float mx = -3e38f;
#pragma unroll
    for (int ii = 0; ii < 8; ++ii) {
        int idx = b * T_ + tid + ii * 256;
        float s = scores_p[idx] + scores_p[M_ + idx] + scores_p[2 * M_ + idx] + scores_p[3 * M_ + idx];
        s = (mask[idx] == 0) ? -1e9f : s;
        val[ii] = s;
        mx = fmaxf(mx, s);
    }
#pragma unroll
    for (int m = 1; m <= 32; m <<= 1) mx = fmaxf(mx, __shfl_xor(mx, m));
    if (lane == 0) sm[0][w] = mx;
    __syncthreads();
    mx = fmaxf(fmaxf(sm[0][0], sm[0][1]), fmaxf(sm[0][2], sm[0][3]));
    float lsum = 0.f;
#pragma unroll
    for (int ii = 0; ii < 8; ++ii) {
        val[ii] = __expf(val[ii] - mx);
        lsum += val[ii];
    }
#pragma unroll
    for (int m = 1; m <= 32; m <<= 1) lsum += __shfl_xor(lsum, m);
    if (lane == 0) sm[1][w] = lsum;
    __syncthreads();
    float inv = 1.0f / (sm[1][0] + sm[1][1] + sm[1][2] + sm[1][3]);

    if (seg == 0) {
#pragma unroll
        for (int ii = 0; ii < 8; ++ii)
            attn[b * T_ + tid + ii * 256] = val[ii] * inv;
    }
    // this block's 128 attn weights -> LDS (t = tid + ii*256 in [seg*128, seg*128+128))
    {
        int half = seg & 1, ii0 = seg >> 1;
        if ((tid >> 7) == half) wa[tid & 127] = val[ii0] * inv;
    }
    __syncthreads();

    // ---- context partial: stream 128 contiguous enc rows (4 KB each) ----
    int t0 = seg * 128;
    const float* ep = &enc[((size_t)b * T_ + t0) * H_ + tid * 4];
    f32x4 acc = {0.f, 0.f, 0.f, 0.f};
#pragma unroll 8
    for (int t = 0; t < 128; ++t) {
        float a = wa[t];                        // LDS broadcast
        acc += a * *(const f32x4*)(ep + (size_t)t * H_);
    }
    *(f32x4*)&ctxp[((size_t)(seg * B_ + b)) * H_ + tid * 4] = acc;
}

// ---------------- K3: deterministic reduce of the 16 segment partials ----------------
__global__ __launch_bounds__(256) void k_red(const float* __restrict__ ctxp,
                                             float* __restrict__ ctx) {
    int i = blockIdx.x * 256 + threadIdx.x;    // 0..32767 over b*H+h
    float s = 0.f;
#pragma unroll
    for (int sg = 0; sg < 16; ++sg)
        s += ctxp[(size_t)sg * (B_ * H_) + i];
    ctx[i] = s;
}

extern "C" void kernel_launch(void* const* d_in, const int* in_sizes, int n_in,
                              void* d_out, int out_size, void* d_ws, size_t ws_size,
                              hipStream_t stream) {
    (void)in_sizes; (void)n_in; (void)out_size; (void)ws_size;
    const float* dec  = (const float*)d_in[0];
    const float* enc  = (const float*)d_in[1];
    const int*   mask = (const int*)d_in[2];
    const float* We   = (const float*)d_in[3];
    const float* Wd   = (const float*)d_in[4];
    const float* v    = (const float*)d_in[5];

    float* out = (float*)d_out;                 // [0,32768) context ; [32768,98304) attn
    char* ws = (char*)d_ws;
    float*  decp     = (float*)ws;                                   // 128 KB
    float*  scores_p = (float*)(ws + 131072);                        // 1 MB
    __bf16* Wt       = (__bf16*)(ws + 131072 + 1048576);             // 2 MB
    float*  ctxp     = (float*)(ws + 131072 + 1048576 + 2097152);    // 2 MB

    k_prep  <<<1024, 256, 0, stream>>>(We, Wt, dec, Wd, decp);
    k_scores<<<4096, 256, 0, stream>>>(enc, decp, Wt, v, scores_p);
    k_ctx   <<<512, 256, 0, stream>>>(scores_p, mask, enc, out + B_ * H_, ctxp);
    k_red   <<<128, 256, 0, stream>>>(ctxp, out);
}

// Round 4
// 563.320 us; speedup vs baseline: 1.2620x; 1.0115x over previous
//
#include <hip/hip_runtime.h>
#include <hip/hip_bf16.h>
#include <stdint.h>

#define B_ 32
#define T_ 2048
#define H_ 1024
#define M_ (B_*T_)

typedef __bf16 bf16x8 __attribute__((ext_vector_type(8)));
typedef float  f32x4  __attribute__((ext_vector_type(4)));
typedef float  f32x16 __attribute__((ext_vector_type(16)));

__device__ __forceinline__ float tanh_fast(float x) {
    float e = __expf(2.0f * x);
    return 1.0f - 2.0f / (e + 1.0f);
}

__device__ __forceinline__ bf16x8 cvt2(f32x4 f0, f32x4 f1) {
    bf16x8 h;
    h[0] = (__bf16)f0[0]; h[1] = (__bf16)f0[1]; h[2] = (__bf16)f0[2]; h[3] = (__bf16)f0[3];
    h[4] = (__bf16)f1[0]; h[5] = (__bf16)f1[1]; h[6] = (__bf16)f1[2]; h[7] = (__bf16)f1[3];
    return h;
}

// ---------------- K0: fused prep (W_enc -> bf16 fragment tiles ; dec_p matvec) ----------------
// Wt part: 512 blocks. dec-matvec: 64 blocks = 16 oc x 4 bg; each block computes 8 b x 64 o
// with dec rows LDS-broadcast (wave-uniform reads) and Wd streamed once per bg (16 MB total).
__global__ __launch_bounds__(256) void k_prep(const float* __restrict__ We,
                                              __bf16* __restrict__ Wt,
                                              const float* __restrict__ dec,
                                              const float* __restrict__ Wd,
                                              float* __restrict__ decp) {
    __shared__ float dec8[8][1024];
    int bx = blockIdx.x;
    int tid = threadIdx.x;
    if (bx < 512) {
        int tg = bx * 256 + tid;             // 131072 cells
        int lane = tg & 63;
        int c = (tg >> 6) & 31;
        int s = tg >> 11;                    // 0..63
        int o = c * 32 + (lane & 31);
        int k = s * 16 + (lane >> 5) * 8;
        const f32x4* src = (const f32x4*)&We[(size_t)o * H_ + k];
        *(bf16x8*)&Wt[(size_t)tg * 8] = cvt2(src[0], src[1]);
    } else {
        int bx2 = bx - 512;                  // 0..63
        int oc = bx2 >> 2, bg = bx2 & 3;
        int b0 = bg * 8;
        {   // stage 8 dec rows into LDS
            int r = tid >> 5, c4 = (tid & 31) * 4;
            const float* drp = &dec[(size_t)(b0 + r) * H_];
#pragma unroll
            for (int j = 0; j < 8; ++j)
                *(f32x4*)&dec8[r][c4 + j * 128] = *(const f32x4*)&drp[c4 + j * 128];
        }
        __syncthreads();
        int ol = tid & 63, bi = tid >> 6;    // wave-uniform bi -> LDS broadcast reads
        int o = oc * 64 + ol;
        const f32x4* wr = (const f32x4*)&Wd[(size_t)o * H_];
        const f32x4* d0 = (const f32x4*)&dec8[bi][0];
        const f32x4* d1 = (const f32x4*)&dec8[bi + 4][0];
        f32x4 a0 = {0.f,0.f,0.f,0.f}, a1 = {0.f,0.f,0.f,0.f};
#pragma unroll 8
        for (int i = 0; i < 256; ++i) {
            f32x4 wv = wr[i];
            a0 += wv * d0[i];
            a1 += wv * d1[i];
        }
        decp[(b0 + bi) * H_ + o]     = a0[0] + a0[1] + a0[2] + a0[3];
        decp[(b0 + bi + 4) * H_ + o] = a1[0] + a1[1] + a1[2] + a1[3];
    }
}

// ---------------- K1: fused GEMM(32x32x16) + tanh + dot(v) -> score partials ----------------
// 4096 blocks = 1024 row-groups (64 rows) x 4 col-groups (256 cols), 4 waves (Cw=64).
// A in LDS as BF16 (halves LDS-read vs f32: MFMA:LDS = 1:2): reg-staged
// (global f32 loads issued BEFORE the MFMA loop (T14), cvt2 + ds_write after, 1 barrier/chunk,
// true double buffer 2 x 8 KB).
// Read layout: phys cell = (sl*2+rt)*64 + q2*32 + (l5 ^ (sl<<2)) -> every ds_read_b128 is a
// permuted 1024B-contiguous wave read (R2-proven 0-conflict).
// Write: thread (row=16w+(l>>2), sl=l&3) writes lane' = r31^(sl<<2): 2 lanes/bank-quad = free.
__global__ __launch_bounds__(256, 3) void k_scores(const float* __restrict__ enc,
                                                   const float* __restrict__ decp,
                                                   const __bf16* __restrict__ Wt,
                                                   const float* __restrict__ v,
                                                   float* __restrict__ scores_p) {
    __shared__ __bf16 A_lds[2][4096];   // 2 x 8 KB bf16 chunks (64 rows x 64 k, tile order)
    __shared__ float red[4][64];

    const int tid = threadIdx.x;
    const int w = tid >> 6, lane = tid & 63;
    const int l5 = lane & 31, q2 = lane >> 5;

    // XCD-swizzled decode: the 4 col-groups of one row-group share an XCD (L2 A-reuse)
    const int bx = blockIdx.x;
    const int xs = bx & 7;
    const int q = bx >> 3;
    const int nt = q & 3;                   // col-group (256 cols)
    const int rg = (q >> 2) * 8 + xs;       // row-group 0..1023
    const int m0 = rg * 64;
    const int b = m0 >> 11;
    const int cg0 = nt * 8 + w * 2;         // global 32-col tile index

    float dp[2], vvv[2];
#pragma unroll
    for (int ct = 0; ct < 2; ++ct) {
        int col = (cg0 + ct) * 32 + l5;
        dp[ct]  = decp[b * H_ + col];
        vvv[ct] = v[col];
    }

    f32x16 acc[2][2];
#pragma unroll
    for (int rt = 0; rt < 2; ++rt)
#pragma unroll
        for (int ct = 0; ct < 2; ++ct)
#pragma unroll
            for (int g = 0; g < 16; ++g)
                acc[rt][ct][g] = dp[ct];

    // staging geometry: thread covers row sr = 16w + (lane>>2), float window slp*16 (+ck*64)
    const int sr  = w * 16 + (lane >> 2);
    const int slp = lane & 3;
    const float* gsrc = enc + (size_t)(m0 + sr) * H_ + slp * 16;
    const int rtw = sr >> 5, r31 = sr & 31;
    const int wb = ((slp * 2 + rtw) * 64 + (r31 ^ (slp << 2))) * 8;   // bf16 index, q2=0 cell
    // q2=1 cell at wb + 32*8

    // ---- prologue: stage chunk 0 into buf 0 ----
    {
        f32x4 g0 = *(const f32x4*)(gsrc + 0);
        f32x4 g1 = *(const f32x4*)(gsrc + 4);
        f32x4 g2 = *(const f32x4*)(gsrc + 8);
        f32x4 g3 = *(const f32x4*)(gsrc + 12);
        *(bf16x8*)&A_lds[0][wb]       = cvt2(g0, g1);
        *(bf16x8*)&A_lds[0][wb + 256] = cvt2(g2, g3);
    }

    // ---- B ring prologue: slices 0..1 ----
    bf16x8 bb[2][2];
#pragma unroll
    for (int p = 0; p < 2; ++p)
#pragma unroll
        for (int ct = 0; ct < 2; ++ct)
            bb[p][ct] = *(const bf16x8*)&Wt[(((size_t)p * 32 + cg0 + ct) * 64 + lane) * 8];

    __syncthreads();

    int cur = 0;
#pragma unroll 1
    for (int ck = 0; ck < 16; ++ck) {
        // issue global loads for chunk ck+1 FIRST: latency hides under the MFMA loop (T14)
        f32x4 g0, g1, g2, g3;
        if (ck < 15) {
            const float* gp = gsrc + (ck + 1) * 64;
            g0 = *(const f32x4*)(gp + 0);
            g1 = *(const f32x4*)(gp + 4);
            g2 = *(const f32x4*)(gp + 8);
            g3 = *(const f32x4*)(gp + 12);
        }

        const __bf16* buf = A_lds[cur];

#pragma unroll
        for (int sl = 0; sl < 4; ++sl) {
            const int s = ck * 4 + sl;
            // A fragments: permuted-contiguous 1024B wave reads (0-conflict)
            bf16x8 a0 = *(const bf16x8*)&buf[(((sl * 2 + 0) * 64) + q2 * 32 + (l5 ^ (sl << 2))) * 8];
            bf16x8 a1 = *(const bf16x8*)&buf[(((sl * 2 + 1) * 64) + q2 * 32 + (l5 ^ (sl << 2))) * 8];
            bf16x8 w0 = bb[s & 1][0], w1 = bb[s & 1][1];

            // prefetch B slice s+2 (L2-resident Wt) into the slot just freed
            {
                int sn = (s + 2) & 63;
#pragma unroll
                for (int ct = 0; ct < 2; ++ct)
                    bb[s & 1][ct] = *(const bf16x8*)&Wt[(((size_t)sn * 32 + cg0 + ct) * 64 + lane) * 8];
            }

            __builtin_amdgcn_s_setprio(1);
            acc[0][0] = __builtin_amdgcn_mfma_f32_32x32x16_bf16(a0, w0, acc[0][0], 0, 0, 0);
            acc[0][1] = __builtin_amdgcn_mfma_f32_32x32x16_bf16(a0, w1, acc[0][1], 0, 0, 0);
            acc[1][0] = __builtin_amdgcn_mfma_f32_32x32x16_bf16(a1, w0, acc[1][0], 0, 0, 0);
            acc[1][1] = __builtin_amdgcn_mfma_f32_32x32x16_bf16(a1, w1, acc[1][1], 0, 0, 0);
            __builtin_amdgcn_s_setprio(0);
        }

        // write staged chunk ck+1 into the other buffer (no hazard: readers on buf[cur])
        if (ck < 15) {
            __bf16* dst = A_lds[cur ^ 1];
            *(bf16x8*)&dst[wb]       = cvt2(g0, g1);
            *(bf16x8*)&dst[wb + 256] = cvt2(g2, g3);
        }
        __syncthreads();
        cur ^= 1;
    }

    // ---- epilogue ----
    float sp[2][16];
#pragma unroll
    for (int rt = 0; rt < 2; ++rt)
#pragma unroll
        for (int g = 0; g < 16; ++g)
            sp[rt][g] = tanh_fast(acc[rt][0][g]) * vvv[0] + tanh_fast(acc[rt][1][g]) * vvv[1];

#pragma unroll
    for (int rt = 0; rt < 2; ++rt)
#pragma unroll
        for (int g = 0; g < 16; ++g) {
            float s = sp[rt][g];
            s += __shfl_xor(s, 1);
            s += __shfl_xor(s, 2);
            s += __shfl_xor(s, 4);
            s += __shfl_xor(s, 8);
            s += __shfl_xor(s, 16);
            sp[rt][g] = s;
        }

    __syncthreads();
    if (l5 == 0) {
#pragma unroll
        for (int rt = 0; rt < 2; ++rt)
#pragma unroll
            for (int g = 0; g < 16; ++g) {
                int row = rt * 32 + (g & 3) + 8 * (g >> 2) + 4 * q2;
                red[w][row] = sp[rt][g];
            }
    }
    __syncthreads();
    if (tid < 64) {
        float s = red[0][tid] + red[1][tid] + red[2][tid] + red[3][tid];
        scores_p[nt * M_ + m0 + tid] = s;   // per-col-group partial, no atomics
    }
}

// ---------------- K2: fused masked-softmax + context partial ----------------
// 512 blocks = 32 b x 16 segs of 128 rows. Each block redundantly computes the full
// softmax for its batch (40 KB reads, ~free), then streams its 128-row enc segment
// contiguously (4 KB/row). seg==0 block writes the attn output row.
__global__ __launch_bounds__(256) void k_ctx(const float* __restrict__ scores_p,
                                             const int* __restrict__ mask,
                                             const float* __restrict__ enc,
                                             float* __restrict__ attn,
                                             float* __restrict__ ctxp) {
    int bx = blockIdx.x;
    int b = bx >> 4, seg = bx & 15;
    int tid = threadIdx.x;
    int w = tid >> 6, lane = tid & 63;
    __shared__ float sm[2][4];
    __shared__ float wa[128];

    float val[8];
    float mx = -3e38f;
#pragma unroll
    for (int ii = 0; ii < 8; ++ii) {
        int idx = b * T_ + tid + ii * 256;
        float s = scores_p[idx] + scores_p[M_ + idx] + scores_p[2 * M_ + idx] + scores_p[3 * M_ + idx];
        s = (mask[idx] == 0) ? -1e9f : s;
        val[ii] = s;
        mx = fmaxf(mx, s);
    }
#pragma unroll
    for (int m = 1; m <= 32; m <<= 1) mx = fmaxf(mx, __shfl_xor(mx, m));
    if (lane == 0) sm[0][w] = mx;
    __syncthreads();
    mx = fmaxf(fmaxf(sm[0][0], sm[0][1]), fmaxf(sm[0][2], sm[0][3]));
    float lsum = 0.f;
#pragma unroll
    for (int ii = 0; ii < 8; ++ii) {
        val[ii] = __expf(val[ii] - mx);
        lsum += val[ii];
    }
#pragma unroll
    for (int m = 1; m <= 32; m <<= 1) lsum += __shfl_xor(lsum, m);
    if (lane == 0) sm[1][w] = lsum;
    __syncthreads();
    float inv = 1.0f / (sm[1][0] + sm[1][1] + sm[1][2] + sm[1][3]);

    if (seg == 0) {
#pragma unroll
        for (int ii = 0; ii < 8; ++ii)
            attn[b * T_ + tid + ii * 256] = val[ii] * inv;
    }
    // this block's 128 attn weights -> LDS (t = tid + ii*256 in [seg*128, seg*128+128))
    {
        int half = seg & 1, ii0 = seg >> 1;
        if ((tid >> 7) == half) wa[tid & 127] = val[ii0] * inv;
    }
    __syncthreads();

    // ---- context partial: stream 128 contiguous enc rows (4 KB each) ----
    int t0 = seg * 128;
    const float* ep = &enc[((size_t)b * T_ + t0) * H_ + tid * 4];
    f32x4 acc = {0.f, 0.f, 0.f, 0.f};
#pragma unroll 8
    for (int t = 0; t < 128; ++t) {
        float a = wa[t];                        // LDS broadcast
        acc += a * *(const f32x4*)(ep + (size_t)t * H_);
    }
    *(f32x4*)&ctxp[((size_t)(seg * B_ + b)) * H_ + tid * 4] = acc;
}

// ---------------- K3: deterministic reduce of the 16 segment partials ----------------
__global__ __launch_bounds__(256) void k_red(const float* __restrict__ ctxp,
                                             float* __restrict__ ctx) {
    int i = blockIdx.x * 256 + threadIdx.x;    // 0..32767 over b*H+h
    float s = 0.f;
#pragma unroll
    for (int sg = 0; sg < 16; ++sg)
        s += ctxp[(size_t)sg * (B_ * H_) + i];
    ctx[i] = s;
}

extern "C" void kernel_launch(void* const* d_in, const int* in_sizes, int n_in,
                              void* d_out, int out_size, void* d_ws, size_t ws_size,
                              hipStream_t stream) {
    (void)in_sizes; (void)n_in; (void)out_size; (void)ws_size;
    const float* dec  = (const float*)d_in[0];
    const float* enc  = (const float*)d_in[1];
    const int*   mask = (const int*)d_in[2];
    const float* We   = (const float*)d_in[3];
    const float* Wd   = (const float*)d_in[4];
    const float* v    = (const float*)d_in[5];

    float* out = (float*)d_out;                 // [0,32768) context ; [32768,98304) attn
    char* ws = (char*)d_ws;
    float*  decp     = (float*)ws;                                   // 128 KB
    float*  scores_p = (float*)(ws + 131072);                        // 1 MB
    __bf16* Wt       = (__bf16*)(ws + 131072 + 1048576);             // 2 MB
    float*  ctxp     = (float*)(ws + 131072 + 1048576 + 2097152);    // 2 MB

    k_prep  <<<576, 256, 0, stream>>>(We, Wt, dec, Wd, decp);
    k_scores<<<4096, 256, 0, stream>>>(enc, decp, Wt, v, scores_p);
    k_ctx   <<<512, 256, 0, stream>>>(scores_p, mask, enc, out + B_ * H_, ctxp);
    k_red   <<<128, 256, 0, stream>>>(ctxp, out);
}